// Round 7
// baseline (166.847 us; speedup 1.0000x reference)
//
#include <hip/hip_runtime.h>
#include <math.h>

// Fused QWZ deformation + HS-distance kernel, v8: v7b with ONE change --
// plain (write-back) stores instead of __builtin_nontemporal_store.
// Theory: across 6 structural variants (LDS tile / streaming / wide / narrow /
// 31%-64% occupancy / L3-fed vs HBM-fed) duration is pinned at 52-58us while
// write throughput is pinned at 0.78-0.93 TB/s -- the only shared component is
// the nontemporal store path (UC/WC, bypasses L2). dur ~= WRITE/0.93TB/s fits
// every data point including v4's regression (misaligned partial WC lines ->
// more write traffic AND lower BW). v8 routes stores through L2/L3 write-back:
// wave-contiguous 1KB per store inst = full lines, no RFO expected.
#define MESHW 1024   // columns per block
#define RPB   4      // output rows per block
#define TPB   256    // threads; each owns 4 consecutive cols

typedef float vfloat4 __attribute__((ext_vector_type(4)));

struct Raw {
    float4 th, ph, ps;     // theta/phi/psi[n0..n0+3]: angle src for sites n0+1..n0+4
    float4 s01, s23;       // sre sites n0..n0+3 (2 sites per float4)
    float4 i01, i23;       // sim sites n0..n0+3
    float2 er, ei;         // lane-63 extra site (col+4) spinor
    float  eth, eph, eps;  // lane-0: angles for site n0 (n0-1); lane-63: wrap-case angles
    int    n0;             // flat index of first owned site this row
    int    nx;             // lane-63 extra site flat index
};

__device__ __forceinline__ void load_row(Raw& B, int r, int cj, int mesh, int N,
    const float* __restrict__ theta, const float* __restrict__ phi,
    const float* __restrict__ psi, const float2* __restrict__ sre,
    const float2* __restrict__ sim, int lane)
{
    if (r >= mesh) r -= mesh;               // halo row wrap
    const int n0 = r * mesh + cj;           // n0 % 4 == 0 -> 16B aligned
    B.n0 = n0;

    if (n0 + 4 < N) {
        B.th = *(const float4*)(theta + n0);
        B.ph = *(const float4*)(phi   + n0);
        B.ps = *(const float4*)(psi   + n0);
    } else {                                 // last quad: theta has N-1 elems
        B.th = make_float4(theta[n0], theta[n0 + 1], theta[n0 + 2], 0.f);
        B.ph = make_float4(phi[n0],   phi[n0 + 1],   phi[n0 + 2],   0.f);
        B.ps = make_float4(psi[n0],   psi[n0 + 1],   psi[n0 + 2],   0.f);
    }
    const float4* sreq = (const float4*)sre;
    const float4* simq = (const float4*)sim;
    B.s01 = sreq[n0 >> 1];  B.s23 = sreq[(n0 >> 1) + 1];
    B.i01 = simq[n0 >> 1];  B.i23 = simq[(n0 >> 1) + 1];

    if (lane == 0) {                         // angle for site n0 (prev wave's col)
        int a = (n0 > 0) ? n0 - 1 : 0;       // origin's value unused
        B.eth = theta[a]; B.eph = phi[a]; B.eps = psi[a];
    }
    if (lane == 63) {                        // redundant overlap site at col+4
        int jn = cj + 4; if (jn >= mesh) jn -= mesh;
        int nx = r * mesh + jn;
        B.nx = nx;
        B.er = sre[nx]; B.ei = sim[nx];
        if (jn == 0) {                       // wrapped: angles not in our quad
            int a = (nx > 0) ? nx - 1 : 0;
            B.eth = theta[a]; B.eph = phi[a]; B.eps = psi[a];
        }
    }
}

__device__ __forceinline__ float4 deform1(float th, float ph, float ps,
                                          float2 r, float2 im, bool origin) {
    float st, ct, sp, cp, sq, cq;
    __sincosf(th, &st, &ct);
    __sincosf(ph, &sp, &cp);
    __sincosf(ps, &sq, &cq);
    float a = ct * cp;   // su_re diag
    float b = st * cq;   // su_re off-diag
    float c = ct * sp;   // su_im diag
    float d = st * sq;   // su_im off-diag
    float4 d4;
    d4.x = a * r.x - b * r.y - c * im.x + d * im.y;
    d4.y = b * r.x + a * r.y + d * im.x + c * im.y;
    d4.z = a * im.x - b * im.y + c * r.x - d * r.y;
    d4.w = b * im.x + a * im.y - d * r.x - c * r.y;
    if (origin) d4 = make_float4(r.x, r.y, im.x, im.y);  // site 0 undeformed
    return d4;
}

__device__ __forceinline__ void deform_row(const Raw& B, float4 A[4],
                                           float4& Aext, int lane)
{
    // angle for site n0: previous lane's th.w (contiguous cols within a wave)
    float thm = __shfl_up(B.th.w, 1, 64);
    float phm = __shfl_up(B.ph.w, 1, 64);
    float psm = __shfl_up(B.ps.w, 1, 64);
    if (lane == 0) { thm = B.eth; phm = B.eph; psm = B.eps; }

    A[0] = deform1(thm,    phm,    psm,
                   make_float2(B.s01.x, B.s01.y), make_float2(B.i01.x, B.i01.y),
                   B.n0 == 0);
    A[1] = deform1(B.th.x, B.ph.x, B.ps.x,
                   make_float2(B.s01.z, B.s01.w), make_float2(B.i01.z, B.i01.w),
                   false);
    A[2] = deform1(B.th.y, B.ph.y, B.ps.y,
                   make_float2(B.s23.x, B.s23.y), make_float2(B.i23.x, B.i23.y),
                   false);
    A[3] = deform1(B.th.z, B.ph.z, B.ps.z,
                   make_float2(B.s23.z, B.s23.w), make_float2(B.i23.z, B.i23.w),
                   false);
    if (lane == 63) {                        // overlap site col+4
        float et = B.th.w, ep = B.ph.w, eq = B.ps.w;   // angle idx n0+3 = nx-1
        if (B.nx != B.n0 + 4) { et = B.eth; ep = B.eph; eq = B.eps; }  // wrapped
        Aext = deform1(et, ep, eq, B.er, B.ei, B.nx == 0);
    }
}

__device__ __forceinline__ float hsdist(float4 A, float4 B) {
    float rr = A.x * B.x + A.y * B.y + A.z * B.z + A.w * B.w;
    float ri = A.x * B.z + A.y * B.w - A.z * B.x - A.w * B.y;
    return sqrtf(fabsf(1.0f - rr * rr - ri * ri));
}

__device__ __forceinline__ float4 shift_in(const float4 A0, const float4 Aext,
                                           int lane)
{
    float4 n;
    n.x = __shfl_down(A0.x, 1, 64);
    n.y = __shfl_down(A0.y, 1, 64);
    n.z = __shfl_down(A0.z, 1, 64);
    n.w = __shfl_down(A0.w, 1, 64);
    if (lane == 63) n = Aext;               // cross-wave / seam overlap site
    return n;
}

__device__ __forceinline__ void store4(float* p, float a, float b,
                                       float c, float d)
{
    vfloat4 q = {a, b, c, d};
    *(vfloat4*)p = q;                       // plain write-back store (v8 change)
}

__device__ __forceinline__ void emit_row(const float4 A[4], const float4 Aext,
    const float4 Bv[4], const float4 Bext, int row, int cj, int mesh, int N,
    float* __restrict__ out, int lane)
{
    const float4 An = shift_in(A[0], Aext, lane);    // deformed (row, col+4)
    const float4 Bn = shift_in(Bv[0], Bext, lane);   // deformed (row+1, col+4)

    const int site = row * mesh + cj;
    store4(out + site,
           hsdist(A[0], A[1]), hsdist(A[1], A[2]),
           hsdist(A[2], A[3]), hsdist(A[3], An));
    store4(out + N + site,
           hsdist(A[0], Bv[0]), hsdist(A[1], Bv[1]),
           hsdist(A[2], Bv[2]), hsdist(A[3], Bv[3]));
    store4(out + 2 * N + site,
           hsdist(A[0], Bv[1]), hsdist(A[1], Bv[2]),
           hsdist(A[2], Bv[3]), hsdist(A[3], Bn));
}

__global__ __launch_bounds__(TPB, 4) void qwz_deform_dirichlet_kernel(
    const float* __restrict__ theta,
    const float* __restrict__ phi,
    const float* __restrict__ psi,
    const float2* __restrict__ sre,
    const float2* __restrict__ sim,
    float* __restrict__ out,          // [3, mesh, mesh]
    int mesh)
{
    const int N = mesh * mesh;
    const int tid  = threadIdx.x;
    const int lane = tid & 63;
    const int cj = blockIdx.x * MESHW + 4 * tid;   // first owned column
    const int r0 = blockIdx.y * RPB;

    Raw ra, rb;
    float4 A[4], B[4], Aext, Bext;

    // prologue: rows r0 and r0+1 issued back-to-back, then deform r0
    load_row(ra, r0,     cj, mesh, N, theta, phi, psi, sre, sim, lane);
    load_row(rb, r0 + 1, cj, mesh, N, theta, phi, psi, sre, sim, lane);
    deform_row(ra, A, Aext, lane);

    // k=0: prefetch r0+2, finish r0+1, emit row r0
    load_row(ra, r0 + 2, cj, mesh, N, theta, phi, psi, sre, sim, lane);
    deform_row(rb, B, Bext, lane);
    emit_row(A, Aext, B, Bext, r0, cj, mesh, N, out, lane);
    A[0] = B[0]; A[1] = B[1]; A[2] = B[2]; A[3] = B[3]; Aext = Bext;

    // k=1
    load_row(rb, r0 + 3, cj, mesh, N, theta, phi, psi, sre, sim, lane);
    deform_row(ra, B, Bext, lane);
    emit_row(A, Aext, B, Bext, r0 + 1, cj, mesh, N, out, lane);
    A[0] = B[0]; A[1] = B[1]; A[2] = B[2]; A[3] = B[3]; Aext = Bext;

    // k=2 (halo row r0+4 may wrap to 0)
    load_row(ra, r0 + 4, cj, mesh, N, theta, phi, psi, sre, sim, lane);
    deform_row(rb, B, Bext, lane);
    emit_row(A, Aext, B, Bext, r0 + 2, cj, mesh, N, out, lane);
    A[0] = B[0]; A[1] = B[1]; A[2] = B[2]; A[3] = B[3]; Aext = Bext;

    // k=3
    deform_row(ra, B, Bext, lane);
    emit_row(A, Aext, B, Bext, r0 + 3, cj, mesh, N, out, lane);
}

extern "C" void kernel_launch(void* const* d_in, const int* in_sizes, int n_in,
                              void* d_out, int out_size, void* d_ws, size_t ws_size,
                              hipStream_t stream) {
    const float* theta = (const float*)d_in[0];
    const float* phi   = (const float*)d_in[1];
    const float* psi   = (const float*)d_in[2];
    const float2* sre  = (const float2*)d_in[3];
    const float2* sim  = (const float2*)d_in[4];
    float* out = (float*)d_out;

    int N = in_sizes[0] + 1;                       // theta has N-1 elements
    int mesh = (int)(sqrt((double)N) + 0.5);       // 2048

    dim3 grid(mesh / MESHW, mesh / RPB);           // (2, 512) = 1024 blocks
    dim3 block(TPB);
    qwz_deform_dirichlet_kernel<<<grid, block, 0, stream>>>(
        theta, phi, psi, sre, sim, out, mesh);
}

// Round 9
// 162.095 us; speedup vs baseline: 1.0293x; 1.0293x over previous
//
#include <hip/hip_runtime.h>
#include <math.h>

// Fused QWZ deformation + HS-distance kernel, v9: v5 pipeline at full residency.
// (Resubmission -- round 8 bench died to a container-infrastructure failure,
// no GPU data was produced.)
// Evidence: healthy variants (v2/v3/v5/v6) pin at 2.8-3.3 TB/s combined
// L2-miss traffic; compulsory traffic is 167.9 MB. Low-residency variants
// (v7b 31%) sustain proportionally less BW -> Little's-law suspect. v5 (best,
// 52us) had cross-tile prefetch but 35KB double-buffer LDS capped residency
// at ~50%. v9 = v5 with SINGLE-buffer LDS (17.4KB) + 2 barriers/tile:
// 4 x 512-thr blocks/CU (70KB LDS, 64 VGPR x 2048 thr = full reg file) =
// 100% residency, loads still in flight across every compute phase.
// If time stays ~52us at high occupancy, ~3.2 TB/s is the fabric ceiling
// and v5/v9 are AT the roofline (167.9 MB / 3.25 TB/s = 51.7us).
#define TILE   32
#define HALO   33              // TILE + 1
#define NHALO  (HALO * HALO)   // 1089
#define TSTEPS 4               // tiles per block (vertical walk)
#define TPB    512
#define NBATCH 3               // ceil(NHALO / TPB)

struct Ld { float th, ph, ps; float2 r, im; };

// Issue raw-input loads for one tile's halo into registers (3 batches/thread).
__device__ __forceinline__ void load_tile(
    const float* __restrict__ theta, const float* __restrict__ phi,
    const float* __restrict__ psi, const float2* __restrict__ sre,
    const float2* __restrict__ sim,
    int bi, int bj, int mesh, int tid, Ld P[NBATCH], int nP[NBATCH])
{
#pragma unroll
    for (int b = 0; b < NBATCH; ++b) {
        int l = tid + b * TPB;
        if (l < NHALO) {
            int trow = l / HALO;
            int tcol = l - trow * HALO;
            int gi = bi + trow; if (gi >= mesh) gi -= mesh;
            int gj = bj + tcol; if (gj >= mesh) gj -= mesh;
            int n = gi * mesh + gj;
            nP[b] = n;
            int an = (n > 0) ? n - 1 : 0;   // avoid theta[-1]
            P[b].th = theta[an];
            P[b].ph = phi[an];
            P[b].ps = psi[an];
            P[b].r  = sre[n];
            P[b].im = sim[n];
        }
    }
}

// Deform the prefetched halo (trig + 2x2 complex matmul) and write to LDS.
__device__ __forceinline__ void deform_tile(
    float4* __restrict__ dst, const Ld P[NBATCH], const int nP[NBATCH], int tid)
{
#pragma unroll
    for (int b = 0; b < NBATCH; ++b) {
        int l = tid + b * TPB;
        if (l < NHALO) {
            float st, ct, sp, cp, sq, cq;
            __sincosf(P[b].th, &st, &ct);
            __sincosf(P[b].ph, &sp, &cp);
            __sincosf(P[b].ps, &sq, &cq);
            float a = ct * cp;   // su_re diag
            float bb = st * cq;  // su_re off-diag
            float c = ct * sp;   // su_im diag
            float d = st * sq;   // su_im off-diag
            float2 r = P[b].r, im = P[b].im;
            // d_re = su_re@s_re - su_im@s_im ; d_im = su_re@s_im + su_im@s_re
            float4 d4;
            d4.x = a * r.x - bb * r.y - c * im.x + d * im.y;
            d4.y = bb * r.x + a * r.y + d * im.x + c * im.y;
            d4.z = a * im.x - bb * im.y + c * r.x - d * r.y;
            d4.w = bb * im.x + a * im.y - d * r.x - c * r.y;
            if (nP[b] == 0)      // site 0 keeps undeformed state
                d4 = make_float4(r.x, r.y, im.x, im.y);
            dst[l] = d4;
        }
    }
}

__device__ __forceinline__ float hsdist(float4 A, float4 B) {
    float rr = A.x * B.x + A.y * B.y + A.z * B.z + A.w * B.w;
    float ri = A.x * B.z + A.y * B.w - A.z * B.x - A.w * B.y;
    return sqrtf(fabsf(1.0f - rr * rr - ri * ri));
}

// Compute 2 output rows/thread for one tile from LDS; nontemporal stores.
__device__ __forceinline__ void compute_tile(
    const float4* __restrict__ tl, int rt, int bj, int mesh, int N, int tid,
    float* __restrict__ out)
{
    const int trow = (tid >> 5) << 1;   // 0,2,...,30
    const int tcol = tid & 31;

    float4 A = tl[trow * HALO + tcol];
    float4 V = tl[trow * HALO + tcol + 1];
    int site = (rt + trow) * mesh + (bj + tcol);

#pragma unroll
    for (int k = 0; k < 2; ++k) {
        float4 H = tl[(trow + k + 1) * HALO + tcol];
        float4 D = tl[(trow + k + 1) * HALO + tcol + 1];

        float v = hsdist(A, V);
        float h = hsdist(A, H);
        float d = hsdist(A, D);

        __builtin_nontemporal_store(v, out + site);
        __builtin_nontemporal_store(h, out + N + site);
        __builtin_nontemporal_store(d, out + 2 * N + site);

        A = H; V = D;
        site += mesh;
    }
}

__global__ __launch_bounds__(TPB, 8) void qwz_deform_dirichlet_kernel(
    const float* __restrict__ theta,
    const float* __restrict__ phi,
    const float* __restrict__ psi,
    const float2* __restrict__ sre,
    const float2* __restrict__ sim,
    float* __restrict__ out,          // [3, mesh, mesh]
    int mesh)
{
    const int N = mesh * mesh;
    __shared__ float4 tile[NHALO];    // SINGLE buffer (v9 change): 17.4 KB

    const int bj = blockIdx.x * TILE;            // column origin
    const int r0 = blockIdx.y * (TILE * TSTEPS); // row origin of tile 0
    const int tid = threadIdx.x;

    Ld P[NBATCH]; int nP[NBATCH];

    // ---- prologue: stage tile 0, prefetch tile 1 ----
    load_tile(theta, phi, psi, sre, sim, r0, bj, mesh, tid, P, nP);
    deform_tile(tile, P, nP, tid);
    load_tile(theta, phi, psi, sre, sim, r0 + TILE, bj, mesh, tid, P, nP);
    __syncthreads();

#pragma unroll
    for (int t = 0; t < TSTEPS; ++t) {
        // compute tile t; prefetched raw loads for tile t+1 already in flight
        compute_tile(tile, r0 + t * TILE, bj, mesh, N, tid, out);
        __syncthreads();                 // all reads of tile[] done

        if (t + 1 < TSTEPS) {
            deform_tile(tile, P, nP, tid);      // consume prefetch, overwrite LDS
            if (t + 2 < TSTEPS)
                load_tile(theta, phi, psi, sre, sim,
                          r0 + (t + 2) * TILE, bj, mesh, tid, P, nP);
            __syncthreads();             // writes visible before next compute
        }
    }
}

extern "C" void kernel_launch(void* const* d_in, const int* in_sizes, int n_in,
                              void* d_out, int out_size, void* d_ws, size_t ws_size,
                              hipStream_t stream) {
    const float* theta = (const float*)d_in[0];
    const float* phi   = (const float*)d_in[1];
    const float* psi   = (const float*)d_in[2];
    const float2* sre  = (const float2*)d_in[3];
    const float2* sim  = (const float2*)d_in[4];
    float* out = (float*)d_out;

    int N = in_sizes[0] + 1;                       // theta has N-1 elements
    int mesh = (int)(sqrt((double)N) + 0.5);       // 2048

    dim3 grid(mesh / TILE, mesh / (TILE * TSTEPS)); // (64, 16) = 1024 blocks
    dim3 block(TPB);
    qwz_deform_dirichlet_kernel<<<grid, block, 0, stream>>>(
        theta, phi, psi, sre, sim, out, mesh);
}